// Round 1
// baseline (527.574 us; speedup 1.0000x reference)
//
#include <hip/hip_runtime.h>
#include <stdint.h>
#include <stddef.h>

// Problem constants (fixed by the reference)
constexpr int BATCH = 2;
constexpr int SEQ   = 2048;
constexpr int EMBD  = 2048;
constexpr int NHEAD = 16;
constexpr int HDIM  = 128;
constexpr float SCALE_F = 0.08838834764831845f; // 1/sqrt(128)
constexpr float LOG2E   = 1.4426950408889634f;

typedef short bf16x8 __attribute__((ext_vector_type(8)));
typedef short bf16x4 __attribute__((ext_vector_type(4)));
typedef float f32x4  __attribute__((ext_vector_type(4)));

__device__ __forceinline__ unsigned short f2bf(float f) {
  union { float f; unsigned u; } v; v.f = f;
  unsigned r = v.u + 0x7FFFu + ((v.u >> 16) & 1u);  // RNE
  return (unsigned short)(r >> 16);
}

__device__ __forceinline__ void gload_lds16(const void* g, void* l) {
  __builtin_amdgcn_global_load_lds(
      (const __attribute__((address_space(1))) unsigned int*)g,
      (__attribute__((address_space(3))) unsigned int*)l, 16, 0, 0);
}

// ---------------------------------------------------------------------------
// fp32 -> bf16 cast, vectorized (G13)
// ---------------------------------------------------------------------------
__global__ void cvt_bf16(const float* __restrict__ in, unsigned short* __restrict__ out, int n) {
  int i = (blockIdx.x * blockDim.x + threadIdx.x) * 8;
  const int stride = gridDim.x * blockDim.x * 8;
  for (; i + 7 < n; i += stride) {
    float4 a = *(const float4*)(in + i);
    float4 b = *(const float4*)(in + i + 4);
    union { unsigned short u[8]; int4 v; } r;
    r.u[0] = f2bf(a.x); r.u[1] = f2bf(a.y); r.u[2] = f2bf(a.z); r.u[3] = f2bf(a.w);
    r.u[4] = f2bf(b.x); r.u[5] = f2bf(b.y); r.u[6] = f2bf(b.z); r.u[7] = f2bf(b.w);
    *(int4*)(out + i) = r.v;
  }
}

// ---------------------------------------------------------------------------
// GEMM  C[M,N] = A[M,K] * B[N,K]^T  (both row-major bf16, K contiguous)
// m97 structure: 128x128 tile, BK=32, 4 waves (2x2) x 64x64, global_load_lds
// width 16, double-buffered LDS, XOR-swizzle via pre-swizzled global source.
// ---------------------------------------------------------------------------
struct EpiQKV {
  const float* bias;
  unsigned short* qs; unsigned short* ks; unsigned short* vs;
  __device__ void operator()(int row, int col, float v) const {
    float val = v + bias[col];
    const int which = col >> 11;          // 0:q 1:k 2:v
    const int h = (col >> 7) & 15;
    const int d = col & 127;
    const int b = row >> 11, l = row & (SEQ - 1);
    const unsigned idx = (((unsigned)(b * NHEAD + h) * SEQ) + l) * HDIM + d;
    if (which == 0)      qs[idx] = f2bf(val * SCALE_F);  // pre-scale Q
    else if (which == 1) ks[idx] = f2bf(val);
    else                 vs[idx] = f2bf(val);
  }
};

struct EpiOut {
  const float* bias;
  float* out;
  __device__ void operator()(int row, int col, float v) const {
    out[(size_t)row * EMBD + col] = v + bias[col];
  }
};

template <class Epi>
__global__ __launch_bounds__(256, 2) void gemm_bt(
    const unsigned short* __restrict__ A, const unsigned short* __restrict__ B,
    int K, Epi epi) {
  // per buffer: A tile [128][32] bf16 (4096 shorts) + B tile (4096 shorts)
  __shared__ __align__(16) unsigned short lds[2][8192];
  const int tid = threadIdx.x;
  const int w = tid >> 6, lane = tid & 63;
  const int g = lane >> 4, lr = lane & 15;
  const int wm = w >> 1, wn = w & 1;
  const int m0 = blockIdx.y * 128, n0 = blockIdx.x * 128;
  const int srow = lane >> 2, sslot = lane & 3;   // staging: row-in-chunk, 16B slot

  f32x4 acc[4][4] = {};

  // LDS[r][s] holds X[r][k0 + (s ^ ((r>>1)&3))*8 .. +8]  (linear dest, swz source)
  auto stage = [&](int buf, int t) {
    const int k0 = t * 32;
#pragma unroll
    for (int c2 = 0; c2 < 2; ++c2) {
      const int chunk = 2 * w + c2;               // 0..7 (16 rows each)
      const int row = chunk * 16 + srow;
      const int kel = k0 + ((sslot ^ ((row >> 1) & 3)) << 3);
      gload_lds16(A + (size_t)(m0 + row) * K + kel, &lds[buf][chunk * 512]);
      gload_lds16(B + (size_t)(n0 + row) * K + kel, &lds[buf][4096 + chunk * 512]);
    }
  };

  const int nt = K >> 5;
  int cur = 0;
  stage(0, 0);
  asm volatile("s_waitcnt vmcnt(0)" ::: "memory");
  __syncthreads();

  for (int t = 0; t < nt; ++t) {
    if (t + 1 < nt) stage(cur ^ 1, t + 1);
    bf16x8 af[4], bq[4];
#pragma unroll
    for (int fr = 0; fr < 4; ++fr) {
      const int r = wm * 64 + fr * 16 + lr;
      af[fr] = *(const bf16x8*)&lds[cur][r * 32 + ((g ^ ((r >> 1) & 3)) << 3)];
      const int rn = wn * 64 + fr * 16 + lr;
      bq[fr] = *(const bf16x8*)&lds[cur][4096 + rn * 32 + ((g ^ ((rn >> 1) & 3)) << 3)];
    }
#pragma unroll
    for (int i = 0; i < 4; ++i)
#pragma unroll
      for (int j = 0; j < 4; ++j)
        acc[i][j] = __builtin_amdgcn_mfma_f32_16x16x32_bf16(af[i], bq[j], acc[i][j], 0, 0, 0);
    asm volatile("s_waitcnt vmcnt(0)" ::: "memory");
    __syncthreads();
    cur ^= 1;
  }

  // C/D layout: col = lane&15, row = (lane>>4)*4 + reg  [measured m89/m91]
#pragma unroll
  for (int i = 0; i < 4; ++i)
#pragma unroll
    for (int j = 0; j < 4; ++j) {
      const int row = m0 + wm * 64 + i * 16 + g * 4;
      const int col = n0 + wn * 64 + j * 16 + lr;
#pragma unroll
      for (int jr = 0; jr < 4; ++jr) epi(row + jr, col, acc[i][j][jr]);
    }
}

// ---------------------------------------------------------------------------
// Flash attention fwd. Grid: B*H*(SEQ/64). 4 waves x 16 q-rows. KT=64.
// Swapped QK^T (mfma(K,Q)) => P^T is lane-local per q-row; PV uses V^T LDS
// tile with XOR swizzle, exploiting MFMA k-permutation freedom.
// q is pre-scaled by 1/sqrt(D). Saves per-row m,l for the attn_avg pass.
// ---------------------------------------------------------------------------
__global__ __launch_bounds__(256, 2) void flash_fwd(
    const unsigned short* __restrict__ qs, const unsigned short* __restrict__ ks,
    const unsigned short* __restrict__ vs, unsigned short* __restrict__ ctx,
    float* __restrict__ m_s, float* __restrict__ l_s) {
  __shared__ __align__(16) unsigned short smem[16384];   // 32 KB
  unsigned short* kt = smem;            // K tile [64][128] bf16, swizzled (16 KB)
  char* vtb = (char*)(smem + 8192);     // V^T tile [128][64] bf16, swizzled (16 KB)

  const int tid = threadIdx.x, w = tid >> 6, lane = tid & 63;
  const int g = lane >> 4, lr = lane & 15;
  const int blk = blockIdx.x;
  const int qt = blk & 31, h = (blk >> 5) & 15, b = blk >> 9;
  const int q0 = qt * 64;
  const size_t bhbase = ((size_t)(b * NHEAD + h)) * SEQ * HDIM;

  // Q fragments in registers (lane: row = lr, k-group g*8 within each 32-chunk)
  const int qrow = q0 + w * 16 + lr;
  bf16x8 qf[4];
#pragma unroll
  for (int kk = 0; kk < 4; ++kk)
    qf[kk] = *(const bf16x8*)(qs + bhbase + (size_t)qrow * HDIM + kk * 32 + g * 8);

  float m_run = -1e30f, l_run = 0.f;
  f32x4 o[8] = {};   // O^T: lane holds O^T[d = fd*16+4g+j][qrow = lr]

  const int p = tid >> 3;           // key-pair 0..31
  const int d0v = (tid & 7) * 16;   // d-range start for V^T staging

  for (int t = 0; t < 32; ++t) {
    const int key0 = t * 64;
    __syncthreads();
    // --- stage K tile: LDS[key][s] = K[key][(s ^ (key&7))*8 ..]
#pragma unroll
    for (int c = 0; c < 4; ++c) {
      const int chunk = w * 4 + c;             // 0..15, 4 rows each
      const int key = chunk * 4 + (lane >> 4);
      const int slot = lane & 15;
      gload_lds16(ks + bhbase + (size_t)(key0 + key) * HDIM + ((slot ^ (key & 7)) * 8),
                  &kt[chunk * 512]);
    }
    // --- stage V^T tile (reg-staged transpose, paired u32 writes)
    {
      const unsigned short* gv = vs + bhbase + (size_t)(key0 + 2 * p) * HDIM + d0v;
      bf16x8 v0a = *(const bf16x8*)gv;
      bf16x8 v0b = *(const bf16x8*)(gv + 8);
      bf16x8 v1a = *(const bf16x8*)(gv + HDIM);
      bf16x8 v1b = *(const bf16x8*)(gv + HDIM + 8);
      const int qv = p >> 1, inner = (p & 1) << 2;
#pragma unroll
      for (int dd = 0; dd < 8; ++dd) {
        const int d = d0v + dd;
        const int S = ((d >> 4) & 7) ^ ((d & 7) << 1);
        unsigned valu = (unsigned)(unsigned short)v0a[dd] | ((unsigned)(unsigned short)v1a[dd] << 16);
        *(unsigned*)(vtb + d * 128 + ((qv ^ S) << 3) + inner) = valu;
      }
#pragma unroll
      for (int dd = 0; dd < 8; ++dd) {
        const int d = d0v + 8 + dd;
        const int S = ((d >> 4) & 7) ^ ((d & 7) << 1);
        unsigned valu = (unsigned)(unsigned short)v0b[dd] | ((unsigned)(unsigned short)v1b[dd] << 16);
        *(unsigned*)(vtb + d * 128 + ((qv ^ S) << 3) + inner) = valu;
      }
    }
    __syncthreads();

    // --- S^T = K * Q^T : st[fc][j] = S[key=fc*16+4g+j][qrow=lr]
    f32x4 st[4] = {};
#pragma unroll
    for (int kk = 0; kk < 4; ++kk)
#pragma unroll
      for (int fc = 0; fc < 4; ++fc) {
        const int key = fc * 16 + lr;
        const int slotR = kk * 4 + g;
        bf16x8 kf = *(const bf16x8*)&kt[key * 128 + ((slotR ^ (key & 7)) << 3)];
        st[fc] = __builtin_amdgcn_mfma_f32_16x16x32_bf16(kf, qf[kk], st[fc], 0, 0, 0);
      }

    // --- online softmax (per q-row: reduce over 16 local + lanes ^16,^32)
    float tmax = -1e30f;
#pragma unroll
    for (int fc = 0; fc < 4; ++fc)
#pragma unroll
      for (int j = 0; j < 4; ++j) tmax = fmaxf(tmax, st[fc][j]);
    tmax = fmaxf(tmax, __shfl_xor(tmax, 16));
    tmax = fmaxf(tmax, __shfl_xor(tmax, 32));
    const float m_new = fmaxf(m_run, tmax);
    const float corr = __builtin_exp2f((m_run - m_new) * LOG2E);
    float pt[4][4];
    float tsum = 0.f;
#pragma unroll
    for (int fc = 0; fc < 4; ++fc)
#pragma unroll
      for (int j = 0; j < 4; ++j) {
        const float e = __builtin_exp2f((st[fc][j] - m_new) * LOG2E);
        pt[fc][j] = e; tsum += e;
      }
    tsum += __shfl_xor(tsum, 16);
    tsum += __shfl_xor(tsum, 32);
    l_run = l_run * corr + tsum;
    m_run = m_new;
#pragma unroll
    for (int fd = 0; fd < 8; ++fd)
#pragma unroll
      for (int j = 0; j < 4; ++j) o[fd][j] *= corr;

    // --- P^T bf16 frags; k-mapping: jj<4 -> key c*32+4g+jj, jj>=4 -> +16
    bf16x8 pb[2];
#pragma unroll
    for (int c = 0; c < 2; ++c)
#pragma unroll
      for (int j = 0; j < 4; ++j) {
        pb[c][j]     = (short)f2bf(pt[2 * c][j]);
        pb[c][4 + j] = (short)f2bf(pt[2 * c + 1][j]);
      }

    // --- O^T += V^T * P^T  (A-frag from swizzled V^T with matching k-mapping)
#pragma unroll
    for (int fd = 0; fd < 8; ++fd) {
      const int d = fd * 16 + lr;
      const int S = ((d >> 4) & 7) ^ ((d & 7) << 1);
#pragma unroll
      for (int c = 0; c < 2; ++c) {
        bf16x4 va = *(const bf16x4*)(vtb + d * 128 + (((c * 8 + g) ^ S) << 3));
        bf16x4 vb = *(const bf16x4*)(vtb + d * 128 + (((c * 8 + 4 + g) ^ S) << 3));
        bf16x8 vf;
        vf[0] = va[0]; vf[1] = va[1]; vf[2] = va[2]; vf[3] = va[3];
        vf[4] = vb[0]; vf[5] = vb[1]; vf[6] = vb[2]; vf[7] = vb[3];
        o[fd] = __builtin_amdgcn_mfma_f32_16x16x32_bf16(vf, pb[c], o[fd], 0, 0, 0);
      }
    }
  }

  // --- epilogue: normalize, transpose through LDS, coalesced bf16x8 stores
  const float inv_l = 1.0f / l_run;
  __syncthreads();
  unsigned short* trp = smem + w * 2176;   // [16 rows][136 shorts] per wave
#pragma unroll
  for (int fd = 0; fd < 8; ++fd)
#pragma unroll
    for (int jp = 0; jp < 2; ++jp) {
      const int d = fd * 16 + 4 * g + 2 * jp;
      unsigned valu = (unsigned)f2bf(o[fd][2 * jp] * inv_l) |
                      ((unsigned)f2bf(o[fd][2 * jp + 1] * inv_l) << 16);
      *(unsigned*)((char*)trp + lr * 272 + d * 2) = valu;
    }
  __syncthreads();
#pragma unroll
  for (int r4 = 0; r4 < 4; ++r4) {
    const int row = r4 * 4 + g;
    bf16x8 valv = *(const bf16x8*)((char*)trp + row * 272 + lr * 16);
    *(bf16x8*)(ctx + (size_t)(b * SEQ + q0 + w * 16 + row) * EMBD + h * HDIM + lr * 8) = valv;
  }
  if (g == 0) {
    const int ridx = (b * NHEAD + h) * SEQ + q0 + w * 16 + lr;
    m_s[ridx] = m_run;
    l_s[ridx] = l_run;
  }
}

// ---------------------------------------------------------------------------
// attn_avg: per block = (b, 16 q-rows, 256 keys); loop all 16 heads so the
// head-mean is local (no atomics). Recompute S^T from saved (m,l).
// ---------------------------------------------------------------------------
__global__ __launch_bounds__(256, 2) void attn_avg_k(
    const unsigned short* __restrict__ qs, const unsigned short* __restrict__ ks,
    const float* __restrict__ m_s, const float* __restrict__ l_s,
    float* __restrict__ out) {
  __shared__ __align__(16) unsigned short kt[32768];   // K tile [256][128] bf16, 64 KB
  const int tid = threadIdx.x, w = tid >> 6, lane = tid & 63;
  const int g = lane >> 4, lr = lane & 15;
  const int blk = blockIdx.x;
  const int ktile = blk & 7, qt = (blk >> 3) & 127, b = blk >> 10;
  const int q0 = qt * 16, k0 = ktile * 256;

  float acc[4][4] = {};
  for (int h = 0; h < NHEAD; ++h) {
    const size_t bh = ((size_t)(b * NHEAD + h)) * SEQ * HDIM;
    __syncthreads();
#pragma unroll
    for (int c = 0; c < 16; ++c) {
      const int chunk = w * 16 + c;
      const int key = chunk * 4 + (lane >> 4);
      const int slot = lane & 15;
      gload_lds16(ks + bh + (size_t)(k0 + key) * HDIM + ((slot ^ (key & 7)) * 8),
                  &kt[chunk * 512]);
    }
    __syncthreads();
    bf16x8 qf[4];
#pragma unroll
    for (int kk = 0; kk < 4; ++kk)
      qf[kk] = *(const bf16x8*)(qs + bh + (size_t)(q0 + lr) * HDIM + kk * 32 + g * 8);
    const float mrow = m_s[(b * NHEAD + h) * SEQ + q0 + lr];
    const float invl = 1.0f / l_s[(b * NHEAD + h) * SEQ + q0 + lr];
    f32x4 st[4] = {};
#pragma unroll
    for (int kk = 0; kk < 4; ++kk)
#pragma unroll
      for (int fc = 0; fc < 4; ++fc) {
        const int key = w * 64 + fc * 16 + lr;
        const int slotR = kk * 4 + g;
        bf16x8 kf = *(const bf16x8*)&kt[key * 128 + ((slotR ^ (key & 7)) << 3)];
        st[fc] = __builtin_amdgcn_mfma_f32_16x16x32_bf16(kf, qf[kk], st[fc], 0, 0, 0);
      }
#pragma unroll
    for (int fc = 0; fc < 4; ++fc)
#pragma unroll
      for (int j = 0; j < 4; ++j)
        acc[fc][j] += __builtin_exp2f((st[fc][j] - mrow) * LOG2E) * invl;
  }
  // transpose via LDS (stride 65 to dodge banks) then coalesced f32 stores
  __syncthreads();
  float* tr = (float*)kt + w * (16 * 65);
#pragma unroll
  for (int fc = 0; fc < 4; ++fc)
#pragma unroll
    for (int j = 0; j < 4; ++j)
      tr[lr * 65 + fc * 16 + 4 * g + j] = acc[fc][j] * 0.0625f;
  __syncthreads();
#pragma unroll
  for (int q = 0; q < 16; ++q) {
    const float v = tr[q * 65 + lane];
    out[(size_t)(b * SEQ + q0 + q) * SEQ + k0 + w * 64 + lane] = v;
  }
}

// ---------------------------------------------------------------------------
extern "C" void kernel_launch(void* const* d_in, const int* in_sizes, int n_in,
                              void* d_out, int out_size, void* d_ws, size_t ws_size,
                              hipStream_t stream) {
  const float* query = (const float*)d_in[0];
  // d_in[1] (key), d_in[2] (value) are ignored by the reference module
  const float* W_in  = (const float*)d_in[3];
  const float* b_in  = (const float*)d_in[4];
  const float* W_out = (const float*)d_in[5];
  const float* b_out = (const float*)d_in[6];

  float* out      = (float*)d_out;                       // [B,L,E]
  float* attn_avg = out + (size_t)BATCH * SEQ * EMBD;    // [B,L,L]

  char* ws = (char*)d_ws;
  auto take = [&](size_t bytes) { char* p = ws; ws += bytes; return p; };
  const size_t szBLE = (size_t)BATCH * SEQ * EMBD * 2;   // bf16 [B*L, E]
  unsigned short* qbf = (unsigned short*)take(szBLE);
  unsigned short* wi  = (unsigned short*)take((size_t)3 * EMBD * EMBD * 2);
  unsigned short* wo  = (unsigned short*)take((size_t)EMBD * EMBD * 2);
  unsigned short* qsb = (unsigned short*)take(szBLE);    // [B,H,L,D] pre-scaled
  unsigned short* ksb = (unsigned short*)take(szBLE);
  unsigned short* vsb = (unsigned short*)take(szBLE);
  unsigned short* ctx = (unsigned short*)take(szBLE);    // [B,L,H,D] == [B*L, E]
  float* m_s = (float*)take((size_t)BATCH * NHEAD * SEQ * 4);
  float* l_s = (float*)take((size_t)BATCH * NHEAD * SEQ * 4);

  cvt_bf16<<<1024, 256, 0, stream>>>(query, qbf, BATCH * SEQ * EMBD);
  cvt_bf16<<<2048, 256, 0, stream>>>(W_in, wi, 3 * EMBD * EMBD);
  cvt_bf16<<<1024, 256, 0, stream>>>(W_out, wo, EMBD * EMBD);

  // qkv = query @ W_in^T + b_in  (M=4096, N=6144, K=2048), fused split/reshape
  gemm_bt<EpiQKV><<<dim3(48, 32), 256, 0, stream>>>(qbf, wi, EMBD,
                                                    EpiQKV{b_in, qsb, ksb, vsb});
  // attention (writes ctx, m_s, l_s)
  flash_fwd<<<BATCH * NHEAD * (SEQ / 64), 256, 0, stream>>>(qsb, ksb, vsb, ctx, m_s, l_s);
  // out = ctx @ W_out^T + b_out  (M=4096, N=2048, K=2048)
  gemm_bt<EpiOut><<<dim3(16, 32), 256, 0, stream>>>(ctx, wo, EMBD, EpiOut{b_out, out});
  // attn_avg = mean over heads of P
  attn_avg_k<<<BATCH * (SEQ / 16) * (SEQ / 256), 256, 0, stream>>>(qsb, ksb, m_s, l_s, attn_avg);
}

// Round 2
// 481.294 us; speedup vs baseline: 1.0962x; 1.0962x over previous
//
#include <hip/hip_runtime.h>
#include <hip/hip_bf16.h>
#include <stdint.h>
#include <stddef.h>

// Problem constants (fixed by the reference)
constexpr int BATCH = 2;
constexpr int SEQ   = 2048;
constexpr int EMBD  = 2048;
constexpr int NHEAD = 16;
constexpr int HDIM  = 128;
// 1/sqrt(128) * log2(e): scores land in log2-domain -> exp2 directly
constexpr float QSCALE = 0.08838834764831845f * 1.4426950408889634f;

typedef short bf16x8 __attribute__((ext_vector_type(8)));
typedef float f32x4  __attribute__((ext_vector_type(4)));

__device__ __forceinline__ short f2bfs(float f) {
  union { __hip_bfloat16 h; short s; } u;
  u.h = __float2bfloat16(f);   // hardware cvt (RNE), pairs fuse to v_cvt_pk_bf16_f32
  return u.s;
}

__device__ __forceinline__ void gload_lds16(const void* g, void* l) {
  __builtin_amdgcn_global_load_lds(
      (const __attribute__((address_space(1))) unsigned int*)g,
      (__attribute__((address_space(3))) unsigned int*)l, 16, 0, 0);
}

// key index -> position within vti's interleaved row (16B slot holds keys
// {32c+4g..+3, 32c+16+4g..+3} so PV A-frags are single b128 reads)
__device__ __forceinline__ int vperm(int k) {
  return (k & ~31) | (k & 3) | (((k >> 4) & 1) << 2) | (((k >> 2) & 3) << 3);
}

// ---------------------------------------------------------------------------
// fp32 -> bf16 cast, vectorized (G13)
// ---------------------------------------------------------------------------
__global__ void cvt_bf16(const float* __restrict__ in, unsigned short* __restrict__ out, int n) {
  int i = (blockIdx.x * blockDim.x + threadIdx.x) * 8;
  const int stride = gridDim.x * blockDim.x * 8;
  for (; i + 7 < n; i += stride) {
    float4 a = *(const float4*)(in + i);
    float4 b = *(const float4*)(in + i + 4);
    union { unsigned short u[8]; int4 v; } r;
    r.u[0] = (unsigned short)f2bfs(a.x); r.u[1] = (unsigned short)f2bfs(a.y);
    r.u[2] = (unsigned short)f2bfs(a.z); r.u[3] = (unsigned short)f2bfs(a.w);
    r.u[4] = (unsigned short)f2bfs(b.x); r.u[5] = (unsigned short)f2bfs(b.y);
    r.u[6] = (unsigned short)f2bfs(b.z); r.u[7] = (unsigned short)f2bfs(b.w);
    *(int4*)(out + i) = r.v;
  }
}

// ---------------------------------------------------------------------------
// GEMM  C[M,N] = A[M,K] * B[N,K]^T  (m97 structure, 128x128 tile, BK=32)
// ---------------------------------------------------------------------------
struct EpiQKV {
  const float* bias;
  unsigned short* qs; unsigned short* ks; unsigned short* vti;
  __device__ void operator()(int row, int col, float v) const {
    float val = v + bias[col];
    const int which = col >> 11;          // 0:q 1:k 2:v
    const int h = (col >> 7) & 15;
    const int d = col & 127;
    const int b = row >> 11, l = row & (SEQ - 1);
    if (which == 0) {
      qs[(((unsigned)(b * NHEAD + h) * SEQ) + l) * HDIM + d] = (unsigned short)f2bfs(val * QSCALE);
    } else if (which == 1) {
      ks[(((unsigned)(b * NHEAD + h) * SEQ) + l) * HDIM + d] = (unsigned short)f2bfs(val);
    } else {
      // V stored pre-transposed + key-interleaved: [B,H,D,SEQperm]
      vti[(((unsigned)(b * NHEAD + h) * HDIM) + d) * SEQ + vperm(l)] = (unsigned short)f2bfs(val);
    }
  }
};

struct EpiOut {
  const float* bias;
  float* out;
  __device__ void operator()(int row, int col, float v) const {
    out[(size_t)row * EMBD + col] = v + bias[col];
  }
};

template <class Epi>
__global__ __launch_bounds__(256, 2) void gemm_bt(
    const unsigned short* __restrict__ A, const unsigned short* __restrict__ B,
    int K, Epi epi) {
  __shared__ __align__(16) unsigned short lds[2][8192];
  const int tid = threadIdx.x;
  const int w = tid >> 6, lane = tid & 63;
  const int g = lane >> 4, lr = lane & 15;
  const int wm = w >> 1, wn = w & 1;
  const int m0 = blockIdx.y * 128, n0 = blockIdx.x * 128;
  const int srow = lane >> 2, sslot = lane & 3;

  f32x4 acc[4][4] = {};

  auto stage = [&](int buf, int t) {
    const int k0 = t * 32;
#pragma unroll
    for (int c2 = 0; c2 < 2; ++c2) {
      const int chunk = 2 * w + c2;
      const int row = chunk * 16 + srow;
      const int kel = k0 + ((sslot ^ ((row >> 1) & 3)) << 3);
      gload_lds16(A + (size_t)(m0 + row) * K + kel, &lds[buf][chunk * 512]);
      gload_lds16(B + (size_t)(n0 + row) * K + kel, &lds[buf][4096 + chunk * 512]);
    }
  };

  const int nt = K >> 5;
  int cur = 0;
  stage(0, 0);
  asm volatile("s_waitcnt vmcnt(0)" ::: "memory");
  __syncthreads();

  for (int t = 0; t < nt; ++t) {
    if (t + 1 < nt) stage(cur ^ 1, t + 1);
    bf16x8 af[4], bq[4];
#pragma unroll
    for (int fr = 0; fr < 4; ++fr) {
      const int r = wm * 64 + fr * 16 + lr;
      af[fr] = *(const bf16x8*)&lds[cur][r * 32 + ((g ^ ((r >> 1) & 3)) << 3)];
      const int rn = wn * 64 + fr * 16 + lr;
      bq[fr] = *(const bf16x8*)&lds[cur][4096 + rn * 32 + ((g ^ ((rn >> 1) & 3)) << 3)];
    }
#pragma unroll
    for (int i = 0; i < 4; ++i)
#pragma unroll
      for (int j = 0; j < 4; ++j)
        acc[i][j] = __builtin_amdgcn_mfma_f32_16x16x32_bf16(af[i], bq[j], acc[i][j], 0, 0, 0);
    asm volatile("s_waitcnt vmcnt(0)" ::: "memory");
    __syncthreads();
    cur ^= 1;
  }

#pragma unroll
  for (int i = 0; i < 4; ++i)
#pragma unroll
    for (int j = 0; j < 4; ++j) {
      const int row = m0 + wm * 64 + i * 16 + g * 4;
      const int col = n0 + wn * 64 + j * 16 + lr;
#pragma unroll
      for (int jr = 0; jr < 4; ++jr) epi(row + jr, col, acc[i][j][jr]);
    }
}

// ---------------------------------------------------------------------------
// Flash attention fwd. Grid: B*H*(SEQ/64). 4 waves x 16 q-rows. KT=64.
// Swapped QK^T (mfma(K,Q)) => P^T lane-local. V^T pre-transposed in global
// (vti), staged via global_load_lds; PV A-frag = one swizzled ds_read_b128.
// Double-buffered LDS; defer-max (T13); log2-domain scores (exp2 direct).
// ---------------------------------------------------------------------------
__global__ __launch_bounds__(256, 2) void flash_fwd(
    const unsigned short* __restrict__ qs, const unsigned short* __restrict__ ks,
    const unsigned short* __restrict__ vti, unsigned short* __restrict__ ctx,
    float* __restrict__ m_s, float* __restrict__ l_s) {
  __shared__ __align__(16) unsigned short smem[2][16384];  // per buf: K 16KB + V^T 16KB
  const int tid = threadIdx.x, w = tid >> 6, lane = tid & 63;
  const int g = lane >> 4, lr = lane & 15;
  const int blk = blockIdx.x;
  const int qt = blk & 31, h = (blk >> 5) & 15, b = blk >> 9;
  const int q0 = qt * 64;
  const size_t bh = ((size_t)(b * NHEAD + h)) * SEQ * HDIM;

  // Q fragments in registers
  const int qrow = q0 + w * 16 + lr;
  bf16x8 qf[4];
#pragma unroll
  for (int kk = 0; kk < 4; ++kk)
    qf[kk] = *(const bf16x8*)(qs + bh + (size_t)qrow * HDIM + kk * 32 + g * 8);

  float m_run = -1e30f, l_run = 0.f;
  f32x4 o[8] = {};   // O^T: lane holds O^T[d = fd*16+4g+jr][qrow = lr]

  auto stage = [&](int buf, int t) {
    unsigned short* kt = smem[buf];
    unsigned short* vt = smem[buf] + 8192;
    const int key0 = t * 64;
#pragma unroll
    for (int c = 0; c < 4; ++c) {          // K tile [64][128] bf16, row-swizzled
      const int chunk = w * 4 + c;
      const int key = chunk * 4 + (lane >> 4);
      const int slot = lane & 15;
      gload_lds16(ks + bh + (size_t)(key0 + key) * HDIM + ((slot ^ (key & 7)) * 8),
                  &kt[chunk * 512]);
    }
#pragma unroll
    for (int c = 0; c < 4; ++c) {          // V^T tile [128][64] bf16, row-swizzled
      const int chunk = w * 4 + c;
      const int d = chunk * 8 + (lane >> 3);
      const int slot = lane & 7;
      gload_lds16(vti + bh + (size_t)d * SEQ + key0 + ((slot ^ (d & 7)) * 8),
                  &vt[chunk * 512]);
    }
  };

  stage(0, 0);
  asm volatile("s_waitcnt vmcnt(0)" ::: "memory");
  __syncthreads();
  int cur = 0;

  for (int t = 0; t < 32; ++t) {
    if (t + 1 < 32) stage(cur ^ 1, t + 1);
    const unsigned short* kt = smem[cur];
    const unsigned short* vt = smem[cur] + 8192;

    // --- S^T = K * Q^T : st[fc][jr] = S[key=fc*16+4g+jr][q=lr]  (log2 domain)
    f32x4 st[4] = {};
#pragma unroll
    for (int kk = 0; kk < 4; ++kk)
#pragma unroll
      for (int fc = 0; fc < 4; ++fc) {
        const int key = fc * 16 + lr;
        bf16x8 kf = *(const bf16x8*)&kt[key * 128 + (((kk * 4 + g) ^ (key & 7)) << 3)];
        st[fc] = __builtin_amdgcn_mfma_f32_16x16x32_bf16(kf, qf[kk], st[fc], 0, 0, 0);
      }

    // --- online softmax with defer-max (THR=8 in log2 domain)
    float tmax = st[0][0];
#pragma unroll
    for (int fc = 0; fc < 4; ++fc)
#pragma unroll
      for (int j = 0; j < 4; ++j) tmax = fmaxf(tmax, st[fc][j]);
    tmax = fmaxf(tmax, __shfl_xor(tmax, 16));
    tmax = fmaxf(tmax, __shfl_xor(tmax, 32));
    if (!__all(tmax <= m_run + 8.f)) {
      const float m_new = fmaxf(m_run, tmax);
      const float corr = __builtin_exp2f(m_run - m_new);
      l_run *= corr;
#pragma unroll
      for (int fd = 0; fd < 8; ++fd)
#pragma unroll
        for (int j = 0; j < 4; ++j) o[fd][j] *= corr;
      m_run = m_new;
    }
    float pt[4][4];
    float tsum = 0.f;
#pragma unroll
    for (int fc = 0; fc < 4; ++fc)
#pragma unroll
      for (int j = 0; j < 4; ++j) {
        const float e = __builtin_exp2f(st[fc][j] - m_run);
        pt[fc][j] = e; tsum += e;
      }
    tsum += __shfl_xor(tsum, 16);
    tsum += __shfl_xor(tsum, 32);
    l_run += tsum;

    // --- P^T bf16 frags; lane k-mapping per chunk c: {4g..4g+3, 16+4g..+3}
    bf16x8 pb[2];
#pragma unroll
    for (int c = 0; c < 2; ++c)
#pragma unroll
      for (int j = 0; j < 4; ++j) {
        pb[c][j]     = f2bfs(pt[2 * c][j]);
        pb[c][4 + j] = f2bfs(pt[2 * c + 1][j]);
      }

    // --- O^T += V^T * P^T  (A-frag = one b128 from interleaved V^T)
#pragma unroll
    for (int fd = 0; fd < 8; ++fd) {
      const int d = fd * 16 + lr;
#pragma unroll
      for (int c = 0; c < 2; ++c) {
        bf16x8 vf = *(const bf16x8*)&vt[d * 64 + (((c * 4 + g) ^ (d & 7)) << 3)];
        o[fd] = __builtin_amdgcn_mfma_f32_16x16x32_bf16(vf, pb[c], o[fd], 0, 0, 0);
      }
    }

    asm volatile("s_waitcnt vmcnt(0)" ::: "memory");
    __syncthreads();
    cur ^= 1;
  }

  // --- epilogue: normalize, transpose through LDS, coalesced bf16x8 stores
  const float inv_l = 1.0f / l_run;
  unsigned short* trp = smem[0] + w * 2176;   // [16 rows][136 shorts] per wave
#pragma unroll
  for (int fd = 0; fd < 8; ++fd)
#pragma unroll
    for (int jp = 0; jp < 2; ++jp) {
      const int d = fd * 16 + 4 * g + 2 * jp;
      unsigned valu = (unsigned)(unsigned short)f2bfs(o[fd][2 * jp] * inv_l) |
                      ((unsigned)(unsigned short)f2bfs(o[fd][2 * jp + 1] * inv_l) << 16);
      *(unsigned*)((char*)trp + lr * 272 + d * 2) = valu;
    }
  __syncthreads();
#pragma unroll
  for (int r4 = 0; r4 < 4; ++r4) {
    const int row = r4 * 4 + g;
    bf16x8 valv = *(const bf16x8*)((char*)trp + row * 272 + lr * 16);
    *(bf16x8*)(ctx + (size_t)(b * SEQ + q0 + w * 16 + row) * EMBD + h * HDIM + lr * 8) = valv;
  }
  if (g == 0) {
    const int ridx = (b * NHEAD + h) * SEQ + q0 + w * 16 + lr;
    m_s[ridx] = m_run;
    l_s[ridx] = l_run;
  }
}

// ---------------------------------------------------------------------------
// attn_avg: per block = (b, 16 q-rows, 256 keys); loop all 16 heads.
// Recompute P from saved (m,l); scores already log2-domain.
// ---------------------------------------------------------------------------
__global__ __launch_bounds__(256, 2) void attn_avg_k(
    const unsigned short* __restrict__ qs, const unsigned short* __restrict__ ks,
    const float* __restrict__ m_s, const float* __restrict__ l_s,
    float* __restrict__ out) {
  __shared__ __align__(16) unsigned short kt[32768];   // K tile [256][128] bf16, 64 KB
  const int tid = threadIdx.x, w = tid >> 6, lane = tid & 63;
  const int g = lane >> 4, lr = lane & 15;
  const int blk = blockIdx.x;
  const int ktile = blk & 7, qt = (blk >> 3) & 127, b = blk >> 10;
  const int q0 = qt * 16, k0 = ktile * 256;

  float acc[4][4] = {};
  for (int h = 0; h < NHEAD; ++h) {
    const size_t bh = ((size_t)(b * NHEAD + h)) * SEQ * HDIM;
    __syncthreads();
#pragma unroll
    for (int c = 0; c < 16; ++c) {
      const int chunk = w * 16 + c;
      const int key = chunk * 4 + (lane >> 4);
      const int slot = lane & 15;
      gload_lds16(ks + bh + (size_t)(k0 + key) * HDIM + ((slot ^ (key & 7)) * 8),
                  &kt[chunk * 512]);
    }
    asm volatile("s_waitcnt vmcnt(0)" ::: "memory");
    __syncthreads();
    bf16x8 qf[4];
#pragma unroll
    for (int kk = 0; kk < 4; ++kk)
      qf[kk] = *(const bf16x8*)(qs + bh + (size_t)(q0 + lr) * HDIM + kk * 32 + g * 8);
    const float mrow = m_s[(b * NHEAD + h) * SEQ + q0 + lr];
    const float invl = 1.0f / l_s[(b * NHEAD + h) * SEQ + q0 + lr];
    f32x4 st[4] = {};
#pragma unroll
    for (int kk = 0; kk < 4; ++kk)
#pragma unroll
      for (int fc = 0; fc < 4; ++fc) {
        const int key = w * 64 + fc * 16 + lr;
        bf16x8 kf = *(const bf16x8*)&kt[key * 128 + (((kk * 4 + g) ^ (key & 7)) << 3)];
        st[fc] = __builtin_amdgcn_mfma_f32_16x16x32_bf16(kf, qf[kk], st[fc], 0, 0, 0);
      }
#pragma unroll
    for (int fc = 0; fc < 4; ++fc)
#pragma unroll
      for (int j = 0; j < 4; ++j)
        acc[fc][j] += __builtin_exp2f(st[fc][j] - mrow) * invl;
  }
  // transpose via LDS (stride 65 dodges banks) then coalesced f32 stores
  __syncthreads();
  float* tr = (float*)kt + w * (16 * 65);
#pragma unroll
  for (int fc = 0; fc < 4; ++fc)
#pragma unroll
    for (int j = 0; j < 4; ++j)
      tr[lr * 65 + fc * 16 + 4 * g + j] = acc[fc][j] * 0.0625f;
  __syncthreads();
#pragma unroll
  for (int q = 0; q < 16; ++q) {
    const float v = tr[q * 65 + lane];
    out[(size_t)(b * SEQ + q0 + q) * SEQ + k0 + w * 64 + lane] = v;
  }
}

// ---------------------------------------------------------------------------
extern "C" void kernel_launch(void* const* d_in, const int* in_sizes, int n_in,
                              void* d_out, int out_size, void* d_ws, size_t ws_size,
                              hipStream_t stream) {
  const float* query = (const float*)d_in[0];
  // d_in[1] (key), d_in[2] (value) are ignored by the reference module
  const float* W_in  = (const float*)d_in[3];
  const float* b_in  = (const float*)d_in[4];
  const float* W_out = (const float*)d_in[5];
  const float* b_out = (const float*)d_in[6];

  float* out      = (float*)d_out;                       // [B,L,E]
  float* attn_avg = out + (size_t)BATCH * SEQ * EMBD;    // [B,L,L]

  char* ws = (char*)d_ws;
  auto take = [&](size_t bytes) { char* p = ws; ws += bytes; return p; };
  const size_t szBLE = (size_t)BATCH * SEQ * EMBD * 2;   // bf16 [B*L, E]
  unsigned short* qbf = (unsigned short*)take(szBLE);
  unsigned short* wi  = (unsigned short*)take((size_t)3 * EMBD * EMBD * 2);
  unsigned short* wo  = (unsigned short*)take((size_t)EMBD * EMBD * 2);
  unsigned short* qsb = (unsigned short*)take(szBLE);    // [B,H,L,D] *QSCALE
  unsigned short* ksb = (unsigned short*)take(szBLE);    // [B,H,L,D]
  unsigned short* vti = (unsigned short*)take(szBLE);    // [B,H,D,Lperm]
  unsigned short* ctx = (unsigned short*)take(szBLE);    // [B,L,H,D] == [B*L, E]
  float* m_s = (float*)take((size_t)BATCH * NHEAD * SEQ * 4);
  float* l_s = (float*)take((size_t)BATCH * NHEAD * SEQ * 4);

  cvt_bf16<<<1024, 256, 0, stream>>>(query, qbf, BATCH * SEQ * EMBD);
  cvt_bf16<<<2048, 256, 0, stream>>>(W_in, wi, 3 * EMBD * EMBD);
  cvt_bf16<<<1024, 256, 0, stream>>>(W_out, wo, EMBD * EMBD);

  // qkv = query @ W_in^T + b_in  (M=4096, N=6144, K=2048), fused split/reshape/transpose
  gemm_bt<EpiQKV><<<dim3(48, 32), 256, 0, stream>>>(qbf, wi, EMBD,
                                                    EpiQKV{b_in, qsb, ksb, vti});
  // attention (writes ctx, m_s, l_s)
  flash_fwd<<<BATCH * NHEAD * (SEQ / 64), 256, 0, stream>>>(qsb, ksb, vti, ctx, m_s, l_s);
  // out = ctx @ W_out^T + b_out  (M=4096, N=2048, K=2048)
  gemm_bt<EpiOut><<<dim3(16, 32), 256, 0, stream>>>(ctx, wo, EMBD, EpiOut{b_out, out});
  // attn_avg = mean over heads of P
  attn_avg_k<<<BATCH * (SEQ / 16) * (SEQ / 256), 256, 0, stream>>>(qsb, ksb, m_s, l_s, attn_avg);
}

// Round 3
// 411.395 us; speedup vs baseline: 1.2824x; 1.1699x over previous
//
#include <hip/hip_runtime.h>
#include <hip/hip_bf16.h>
#include <stdint.h>
#include <stddef.h>

// Problem constants (fixed by the reference)
constexpr int BATCH = 2;
constexpr int SEQ   = 2048;
constexpr int EMBD  = 2048;
constexpr int NHEAD = 16;
constexpr int HDIM  = 128;
// 1/sqrt(128) * log2(e): scores land in log2-domain -> exp2 directly
constexpr float QSCALE = 0.08838834764831845f * 1.4426950408889634f;

typedef short bf16x8 __attribute__((ext_vector_type(8)));
typedef float f32x4  __attribute__((ext_vector_type(4)));

__device__ __forceinline__ short f2bfs(float f) {
  union { __hip_bfloat16 h; short s; } u;
  u.h = __float2bfloat16(f);   // hardware cvt (RNE), pairs fuse to v_cvt_pk_bf16_f32
  return u.s;
}

__device__ __forceinline__ void gload_lds16(const void* g, void* l) {
  __builtin_amdgcn_global_load_lds(
      (const __attribute__((address_space(1))) unsigned int*)g,
      (__attribute__((address_space(3))) unsigned int*)l, 16, 0, 0);
}

// key index -> position within vti's interleaved row (16B slot holds keys
// {32c+4g..+3, 32c+16+4g..+3} so PV A-frags are single b128 reads)
__device__ __forceinline__ int vperm(int k) {
  return (k & ~31) | (k & 3) | (((k >> 4) & 1) << 2) | (((k >> 2) & 3) << 3);
}

// ---------------------------------------------------------------------------
// fp32 -> bf16 cast, vectorized (G13)
// ---------------------------------------------------------------------------
__global__ void cvt_bf16(const float* __restrict__ in, unsigned short* __restrict__ out, int n) {
  int i = (blockIdx.x * blockDim.x + threadIdx.x) * 8;
  const int stride = gridDim.x * blockDim.x * 8;
  for (; i + 7 < n; i += stride) {
    float4 a = *(const float4*)(in + i);
    float4 b = *(const float4*)(in + i + 4);
    union { unsigned short u[8]; int4 v; } r;
    r.u[0] = (unsigned short)f2bfs(a.x); r.u[1] = (unsigned short)f2bfs(a.y);
    r.u[2] = (unsigned short)f2bfs(a.z); r.u[3] = (unsigned short)f2bfs(a.w);
    r.u[4] = (unsigned short)f2bfs(b.x); r.u[5] = (unsigned short)f2bfs(b.y);
    r.u[6] = (unsigned short)f2bfs(b.z); r.u[7] = (unsigned short)f2bfs(b.w);
    *(int4*)(out + i) = r.v;
  }
}

// ---------------------------------------------------------------------------
// GEMM  C[M,N] = A[M,K] * B[N,K]^T  (m97 structure, 128x128 tile, BK=32)
// ---------------------------------------------------------------------------
struct EpiQKV {
  const float* bias;
  unsigned short* qs; unsigned short* ks; unsigned short* vti;
  __device__ void operator()(int row, int col, float v) const {
    float val = v + bias[col];
    const int which = col >> 11;          // 0:q 1:k 2:v
    const int h = (col >> 7) & 15;
    const int d = col & 127;
    const int b = row >> 11, l = row & (SEQ - 1);
    if (which == 0) {
      qs[(((unsigned)(b * NHEAD + h) * SEQ) + l) * HDIM + d] = (unsigned short)f2bfs(val * QSCALE);
    } else if (which == 1) {
      ks[(((unsigned)(b * NHEAD + h) * SEQ) + l) * HDIM + d] = (unsigned short)f2bfs(val);
    } else {
      // V stored pre-transposed + key-interleaved: [B,H,D,SEQperm]
      vti[(((unsigned)(b * NHEAD + h) * HDIM) + d) * SEQ + vperm(l)] = (unsigned short)f2bfs(val);
    }
  }
};

struct EpiOut {
  const float* bias;
  float* out;
  __device__ void operator()(int row, int col, float v) const {
    out[(size_t)row * EMBD + col] = v + bias[col];
  }
};

template <class Epi>
__global__ __launch_bounds__(256, 2) void gemm_bt(
    const unsigned short* __restrict__ A, const unsigned short* __restrict__ B,
    int K, Epi epi) {
  __shared__ __align__(16) unsigned short lds[2][8192];
  const int tid = threadIdx.x;
  const int w = tid >> 6, lane = tid & 63;
  const int g = lane >> 4, lr = lane & 15;
  const int wm = w >> 1, wn = w & 1;
  const int m0 = blockIdx.y * 128, n0 = blockIdx.x * 128;
  const int srow = lane >> 2, sslot = lane & 3;

  f32x4 acc[4][4] = {};

  auto stage = [&](int buf, int t) {
    const int k0 = t * 32;
#pragma unroll
    for (int c2 = 0; c2 < 2; ++c2) {
      const int chunk = 2 * w + c2;
      const int row = chunk * 16 + srow;
      const int kel = k0 + ((sslot ^ ((row >> 1) & 3)) << 3);
      gload_lds16(A + (size_t)(m0 + row) * K + kel, &lds[buf][chunk * 512]);
      gload_lds16(B + (size_t)(n0 + row) * K + kel, &lds[buf][4096 + chunk * 512]);
    }
  };

  const int nt = K >> 5;
  int cur = 0;
  stage(0, 0);
  asm volatile("s_waitcnt vmcnt(0)" ::: "memory");
  __syncthreads();

  for (int t = 0; t < nt; ++t) {
    if (t + 1 < nt) stage(cur ^ 1, t + 1);
    bf16x8 af[4], bq[4];
#pragma unroll
    for (int fr = 0; fr < 4; ++fr) {
      const int r = wm * 64 + fr * 16 + lr;
      af[fr] = *(const bf16x8*)&lds[cur][r * 32 + ((g ^ ((r >> 1) & 3)) << 3)];
      const int rn = wn * 64 + fr * 16 + lr;
      bq[fr] = *(const bf16x8*)&lds[cur][4096 + rn * 32 + ((g ^ ((rn >> 1) & 3)) << 3)];
    }
#pragma unroll
    for (int i = 0; i < 4; ++i)
#pragma unroll
      for (int j = 0; j < 4; ++j)
        acc[i][j] = __builtin_amdgcn_mfma_f32_16x16x32_bf16(af[i], bq[j], acc[i][j], 0, 0, 0);
    asm volatile("s_waitcnt vmcnt(0)" ::: "memory");
    __syncthreads();
    cur ^= 1;
  }

#pragma unroll
  for (int i = 0; i < 4; ++i)
#pragma unroll
    for (int j = 0; j < 4; ++j) {
      const int row = m0 + wm * 64 + i * 16 + g * 4;
      const int col = n0 + wn * 64 + j * 16 + lr;
#pragma unroll
      for (int jr = 0; jr < 4; ++jr) epi(row + jr, col, acc[i][j][jr]);
    }
}

// ---------------------------------------------------------------------------
// Flash attention fwd. Grid: B*H*(SEQ/64). 4 waves x 16 q-rows. KT=64.
// Swapped QK^T (mfma(K,Q)) => P^T lane-local. V^T pre-transposed in global
// (vti), staged via global_load_lds; PV A-frag = one swizzled ds_read_b128.
// Double-buffered LDS; defer-max (T13); log2-domain scores (exp2 direct).
// Stores c = m + log2(l) + 4 for the attn_avg pass (folds /16 head-mean).
// ---------------------------------------------------------------------------
__global__ __launch_bounds__(256, 2) void flash_fwd(
    const unsigned short* __restrict__ qs, const unsigned short* __restrict__ ks,
    const unsigned short* __restrict__ vti, unsigned short* __restrict__ ctx,
    float* __restrict__ c_s) {
  __shared__ __align__(16) unsigned short smem[2][16384];  // per buf: K 16KB + V^T 16KB
  const int tid = threadIdx.x, w = tid >> 6, lane = tid & 63;
  const int g = lane >> 4, lr = lane & 15;
  const int blk = blockIdx.x;
  const int qt = blk & 31, h = (blk >> 5) & 15, b = blk >> 9;
  const int q0 = qt * 64;
  const size_t bh = ((size_t)(b * NHEAD + h)) * SEQ * HDIM;

  // Q fragments in registers
  const int qrow = q0 + w * 16 + lr;
  bf16x8 qf[4];
#pragma unroll
  for (int kk = 0; kk < 4; ++kk)
    qf[kk] = *(const bf16x8*)(qs + bh + (size_t)qrow * HDIM + kk * 32 + g * 8);

  float m_run = -1e30f, l_run = 0.f;
  f32x4 o[8] = {};   // O^T: lane holds O^T[d = fd*16+4g+jr][qrow = lr]

  auto stage = [&](int buf, int t) {
    unsigned short* kt = smem[buf];
    unsigned short* vt = smem[buf] + 8192;
    const int key0 = t * 64;
#pragma unroll
    for (int c = 0; c < 4; ++c) {          // K tile [64][128] bf16, row-swizzled
      const int chunk = w * 4 + c;
      const int key = chunk * 4 + (lane >> 4);
      const int slot = lane & 15;
      gload_lds16(ks + bh + (size_t)(key0 + key) * HDIM + ((slot ^ (key & 7)) * 8),
                  &kt[chunk * 512]);
    }
#pragma unroll
    for (int c = 0; c < 4; ++c) {          // V^T tile [128][64] bf16, row-swizzled
      const int chunk = w * 4 + c;
      const int d = chunk * 8 + (lane >> 3);
      const int slot = lane & 7;
      gload_lds16(vti + bh + (size_t)d * SEQ + key0 + ((slot ^ (d & 7)) * 8),
                  &vt[chunk * 512]);
    }
  };

  stage(0, 0);
  asm volatile("s_waitcnt vmcnt(0)" ::: "memory");
  __syncthreads();
  int cur = 0;

  for (int t = 0; t < 32; ++t) {
    if (t + 1 < 32) stage(cur ^ 1, t + 1);
    const unsigned short* kt = smem[cur];
    const unsigned short* vt = smem[cur] + 8192;

    // --- S^T = K * Q^T : st[fc][jr] = S[key=fc*16+4g+jr][q=lr]  (log2 domain)
    f32x4 st[4] = {};
#pragma unroll
    for (int kk = 0; kk < 4; ++kk)
#pragma unroll
      for (int fc = 0; fc < 4; ++fc) {
        const int key = fc * 16 + lr;
        bf16x8 kf = *(const bf16x8*)&kt[key * 128 + (((kk * 4 + g) ^ (key & 7)) << 3)];
        st[fc] = __builtin_amdgcn_mfma_f32_16x16x32_bf16(kf, qf[kk], st[fc], 0, 0, 0);
      }

    // --- online softmax with defer-max (THR=8 in log2 domain)
    float tmax = st[0][0];
#pragma unroll
    for (int fc = 0; fc < 4; ++fc)
#pragma unroll
      for (int j = 0; j < 4; ++j) tmax = fmaxf(tmax, st[fc][j]);
    tmax = fmaxf(tmax, __shfl_xor(tmax, 16));
    tmax = fmaxf(tmax, __shfl_xor(tmax, 32));
    if (!__all(tmax <= m_run + 8.f)) {
      const float m_new = fmaxf(m_run, tmax);
      const float corr = __builtin_exp2f(m_run - m_new);
      l_run *= corr;
#pragma unroll
      for (int fd = 0; fd < 8; ++fd)
#pragma unroll
        for (int j = 0; j < 4; ++j) o[fd][j] *= corr;
      m_run = m_new;
    }
    float pt[4][4];
    float tsum = 0.f;
#pragma unroll
    for (int fc = 0; fc < 4; ++fc)
#pragma unroll
      for (int j = 0; j < 4; ++j) {
        const float e = __builtin_exp2f(st[fc][j] - m_run);
        pt[fc][j] = e; tsum += e;
      }
    tsum += __shfl_xor(tsum, 16);
    tsum += __shfl_xor(tsum, 32);
    l_run += tsum;

    // --- P^T bf16 frags; lane k-mapping per chunk c: {4g..4g+3, 16+4g..+3}
    bf16x8 pb[2];
#pragma unroll
    for (int c = 0; c < 2; ++c)
#pragma unroll
      for (int j = 0; j < 4; ++j) {
        pb[c][j]     = f2bfs(pt[2 * c][j]);
        pb[c][4 + j] = f2bfs(pt[2 * c + 1][j]);
      }

    // --- O^T += V^T * P^T  (A-frag = one b128 from interleaved V^T)
#pragma unroll
    for (int fd = 0; fd < 8; ++fd) {
      const int d = fd * 16 + lr;
#pragma unroll
      for (int c = 0; c < 2; ++c) {
        bf16x8 vf = *(const bf16x8*)&vt[d * 64 + (((c * 4 + g) ^ (d & 7)) << 3)];
        o[fd] = __builtin_amdgcn_mfma_f32_16x16x32_bf16(vf, pb[c], o[fd], 0, 0, 0);
      }
    }

    asm volatile("s_waitcnt vmcnt(0)" ::: "memory");
    __syncthreads();
    cur ^= 1;
  }

  // --- epilogue: normalize, transpose through LDS, coalesced bf16x8 stores
  const float inv_l = 1.0f / l_run;
  unsigned short* trp = smem[0] + w * 2176;   // [16 rows][136 shorts] per wave
#pragma unroll
  for (int fd = 0; fd < 8; ++fd)
#pragma unroll
    for (int jp = 0; jp < 2; ++jp) {
      const int d = fd * 16 + 4 * g + 2 * jp;
      unsigned valu = (unsigned)(unsigned short)f2bfs(o[fd][2 * jp] * inv_l) |
                      ((unsigned)(unsigned short)f2bfs(o[fd][2 * jp + 1] * inv_l) << 16);
      *(unsigned*)((char*)trp + lr * 272 + d * 2) = valu;
    }
  __syncthreads();
#pragma unroll
  for (int r4 = 0; r4 < 4; ++r4) {
    const int row = r4 * 4 + g;
    bf16x8 valv = *(const bf16x8*)((char*)trp + row * 272 + lr * 16);
    *(bf16x8*)(ctx + (size_t)(b * SEQ + q0 + w * 16 + row) * EMBD + h * HDIM + lr * 8) = valv;
  }
  if (g == 0) {
    const int ridx = (b * NHEAD + h) * SEQ + q0 + w * 16 + lr;
    c_s[ridx] = m_run + __log2f(l_run) + 4.0f;   // +4 folds the /16 head-mean
  }
}

// ---------------------------------------------------------------------------
// attn_avg v2: GEMM-tiled. Block = 128 q x 128 k output tile; loop 16 heads,
// per head: stage Q-tile + K-tile [128][128] bf16 (64 KB, XOR-swizzled via
// pre-swizzled source), 64 MFMA/wave, acc += exp2(st - c[q]). Non-swapped
// mfma(Q,K) => out[q][k] k-coalesced, no transpose needed.
// ---------------------------------------------------------------------------
__global__ __launch_bounds__(256, 2) void attn_avg_k(
    const unsigned short* __restrict__ qs, const unsigned short* __restrict__ ks,
    const float* __restrict__ c_s, float* __restrict__ out) {
  __shared__ __align__(16) unsigned short lds[32768];   // Q 32KB | K 32KB
  unsigned short* qlds = lds;
  unsigned short* klds = lds + 16384;
  const int tid = threadIdx.x, w = tid >> 6, lane = tid & 63;
  const int g = lane >> 4, lr = lane & 15;
  const int wm = w >> 1, wn = w & 1;
  const int blk = blockIdx.x;
  const int k0 = (blk & 15) * 128, q0 = ((blk >> 4) & 15) * 128, b = blk >> 8;

  const int srow = lane >> 4, sslot = lane & 15;   // staging within 4-row chunk

  f32x4 acc[4][4] = {};

  for (int h = 0; h < NHEAD; ++h) {
    const size_t bh = ((size_t)(b * NHEAD + h)) * SEQ * HDIM;
    if (h) __syncthreads();                 // protect LDS reuse
    // stage Q[128][128] and K[128][128], row-swizzled (slot ^ (row&15))
#pragma unroll
    for (int c = 0; c < 8; ++c) {
      const int chunk = w * 8 + c;          // 0..31, 4 rows each
      const int row = chunk * 4 + srow;
      const int kel = (sslot ^ (row & 15)) * 8;
      gload_lds16(qs + bh + (size_t)(q0 + row) * HDIM + kel, &qlds[chunk * 512]);
      gload_lds16(ks + bh + (size_t)(k0 + row) * HDIM + kel, &klds[chunk * 512]);
    }
    asm volatile("s_waitcnt vmcnt(0)" ::: "memory");
    __syncthreads();

    // S tile: st[i][j], q = wm*64+i*16+g*4+jr, k = wn*64+j*16+lr
    f32x4 st[4][4] = {};
#pragma unroll
    for (int kk = 0; kk < 4; ++kk) {
      bf16x8 af[4], bq[4];
#pragma unroll
      for (int fr = 0; fr < 4; ++fr) {
        const int rq = wm * 64 + fr * 16 + lr;
        af[fr] = *(const bf16x8*)&qlds[rq * 128 + (((kk * 4 + g) ^ (rq & 15)) << 3)];
        const int rk = wn * 64 + fr * 16 + lr;
        bq[fr] = *(const bf16x8*)&klds[rk * 128 + (((kk * 4 + g) ^ (rk & 15)) << 3)];
      }
#pragma unroll
      for (int i = 0; i < 4; ++i)
#pragma unroll
        for (int j = 0; j < 4; ++j)
          st[i][j] = __builtin_amdgcn_mfma_f32_16x16x32_bf16(af[i], bq[j], st[i][j], 0, 0, 0);
    }

    // acc += exp2(st - c[q])   (c = m + log2 l + 4, so /16 is included)
    const int chq = (b * NHEAD + h) * SEQ + q0 + wm * 64 + g * 4;
#pragma unroll
    for (int i = 0; i < 4; ++i) {
      const f32x4 cq = *(const f32x4*)&c_s[chq + i * 16];
#pragma unroll
      for (int j = 0; j < 4; ++j)
#pragma unroll
        for (int jr = 0; jr < 4; ++jr)
          acc[i][j][jr] += __builtin_exp2f(st[i][j][jr] - cq[jr]);
    }
  }

  // store: out[b, q, k], k-coalesced in 16-lane runs
#pragma unroll
  for (int i = 0; i < 4; ++i)
#pragma unroll
    for (int jr = 0; jr < 4; ++jr) {
      const size_t rowoff = (size_t)(b * SEQ + q0 + wm * 64 + i * 16 + g * 4 + jr) * SEQ;
#pragma unroll
      for (int j = 0; j < 4; ++j)
        out[rowoff + k0 + wn * 64 + j * 16 + lr] = acc[i][j][jr];
    }
}

// ---------------------------------------------------------------------------
extern "C" void kernel_launch(void* const* d_in, const int* in_sizes, int n_in,
                              void* d_out, int out_size, void* d_ws, size_t ws_size,
                              hipStream_t stream) {
  const float* query = (const float*)d_in[0];
  // d_in[1] (key), d_in[2] (value) are ignored by the reference module
  const float* W_in  = (const float*)d_in[3];
  const float* b_in  = (const float*)d_in[4];
  const float* W_out = (const float*)d_in[5];
  const float* b_out = (const float*)d_in[6];

  float* out      = (float*)d_out;                       // [B,L,E]
  float* attn_avg = out + (size_t)BATCH * SEQ * EMBD;    // [B,L,L]

  char* ws = (char*)d_ws;
  auto take = [&](size_t bytes) { char* p = ws; ws += bytes; return p; };
  const size_t szBLE = (size_t)BATCH * SEQ * EMBD * 2;   // bf16 [B*L, E]
  unsigned short* qbf = (unsigned short*)take(szBLE);
  unsigned short* wi  = (unsigned short*)take((size_t)3 * EMBD * EMBD * 2);
  unsigned short* wo  = (unsigned short*)take((size_t)EMBD * EMBD * 2);
  unsigned short* qsb = (unsigned short*)take(szBLE);    // [B,H,L,D] *QSCALE
  unsigned short* ksb = (unsigned short*)take(szBLE);    // [B,H,L,D]
  unsigned short* vti = (unsigned short*)take(szBLE);    // [B,H,D,Lperm]
  unsigned short* ctx = (unsigned short*)take(szBLE);    // [B,L,H,D] == [B*L, E]
  float* c_s = (float*)take((size_t)BATCH * NHEAD * SEQ * 4);

  cvt_bf16<<<1024, 256, 0, stream>>>(query, qbf, BATCH * SEQ * EMBD);
  cvt_bf16<<<2048, 256, 0, stream>>>(W_in, wi, 3 * EMBD * EMBD);
  cvt_bf16<<<1024, 256, 0, stream>>>(W_out, wo, EMBD * EMBD);

  // qkv = query @ W_in^T + b_in  (M=4096, N=6144, K=2048), fused split/reshape/transpose
  gemm_bt<EpiQKV><<<dim3(48, 32), 256, 0, stream>>>(qbf, wi, EMBD,
                                                    EpiQKV{b_in, qsb, ksb, vti});
  // attention (writes ctx, c_s)
  flash_fwd<<<BATCH * NHEAD * (SEQ / 64), 256, 0, stream>>>(qsb, ksb, vti, ctx, c_s);
  // out = ctx @ W_out^T + b_out  (M=4096, N=2048, K=2048)
  gemm_bt<EpiOut><<<dim3(16, 32), 256, 0, stream>>>(ctx, wo, EMBD, EpiOut{b_out, out});
  // attn_avg = mean over heads of P (GEMM-tiled recompute)
  attn_avg_k<<<BATCH * (SEQ / 128) * (SEQ / 128), 256, 0, stream>>>(qsb, ksb, c_s, attn_avg);
}